// Round 4
// baseline (735.954 us; speedup 1.0000x reference)
//
#include <hip/hip_runtime.h>
#include <math.h>

#define DIM   4096
#define NITER 20
#define EPSF  1e-10f
#define NB    256
#define NT    1024
#define RPB   16           // rows per block
#define NRG   16           // fallback path

typedef __attribute__((ext_vector_type(4))) unsigned short ushort4_t;
typedef unsigned long long u64;

// ---------- bf16 <-> f32 (range to 2^127 covers E=exp(la) spread) ----------
__device__ __forceinline__ float bf2f(unsigned short b) {
    unsigned int x = ((unsigned int)b) << 16;
    return __builtin_bit_cast(float, x);
}
__device__ __forceinline__ unsigned short f2bf(float f) {
    unsigned int x = __builtin_bit_cast(unsigned int, f);
    x += 0x7fffu + ((x >> 16) & 1u);          // round-to-nearest-even
    return (unsigned short)(x >> 16);
}

// ---------- MALL-coherent access (agent scope bypasses non-coherent L2) ----------
__device__ __forceinline__ u64 ld64(const u64* p) {
    return __hip_atomic_load(p, __ATOMIC_RELAXED, __HIP_MEMORY_SCOPE_AGENT);
}
// tagged dataflow atom: (tag<<32 | f32). Payload + readiness in ONE load.
__device__ __forceinline__ void st_tag(u64* p, float v, unsigned tag) {
    u64 w = ((u64)tag << 32) | (u64)__builtin_bit_cast(unsigned int, v);
    __hip_atomic_store(p, w, __ATOMIC_RELAXED, __HIP_MEMORY_SCOPE_AGENT);
}
__device__ __forceinline__ unsigned tag_of(u64 v) { return (unsigned)(v >> 32); }
__device__ __forceinline__ float    val_of(u64 v) {
    return __builtin_bit_cast(float, (unsigned int)(v & 0xffffffffull));
}

// zero tagged scratch: part (NB*DIM u64 in out) + cgt (DIM u64 in ws)
__global__ __launch_bounds__(256) void zero_scratch(u64* part, u64* cgt) {
    const size_t n = (size_t)NB * DIM;
    size_t idx = (size_t)blockIdx.x * blockDim.x + threadIdx.x;
    size_t stride = (size_t)gridDim.x * blockDim.x;
    for (size_t i = idx; i < n; i += stride) part[i] = 0ull;
    if (idx < DIM) cgt[idx] = 0ull;
}

// ============ persistent multiplicative Sinkhorn, pure tagged dataflow ==========
// Row step:  u_i = 1 / sum_j E_ij * w_j            (block-local, wave<->row)
// Col step:  part[b][j] = sum_{i in blk} E_ij*u_i  (tagged u64, tag=it+1)
//            combine: block b polls+reduces part[0..255][16b..16b+15]
//                     publishes w = 1/colsum as tagged u64 (tag=it+1)
//            refresh: thread t polls only its own 4 tagged w words
// No barriers at all: readiness rides on the data. ABA safety: a block writes
// partials(it+1) only after its refresh(it), which requires all 4096 w(it)
// tags, each published only after that block's combine(it) consumed its
// partial slice. Final out stores overwriting part region: same argument.
__global__ __launch_bounds__(NT, 4) void sinkhorn_flow(
        const float* __restrict__ logits, const float* __restrict__ noise,
        float* __restrict__ out, u64* __restrict__ cgt, u64* __restrict__ part) {
    __shared__ unsigned short lm[RPB][DIM];  // 128 KiB: block's 16 rows of E (bf16)
    __shared__ float          lw[DIM];       //  16 KiB: local copy of w
    __shared__ float          ru[RPB];       // row reciprocals u_i
    __shared__ float4         red[16][4];    //   1 KiB: combine cross-wave stage

    const int t = threadIdx.x;
    const int b = blockIdx.x;
    const int wave = t >> 6, lane = t & 63;
    const int g0 = b * RPB;

    // ---- init: E = exp(logits)/(eps - log(noise+eps)) -> bf16 in LDS + regs ----
    // ec[r] register-caches this thread's column slice (cols 4t..4t+3, all 16
    // rows) — exactly what colpartial and final consume. lm feeds row sums.
    ushort4_t ec[RPB];
#pragma unroll
    for (int r = 0; r < RPB; ++r) {
        const float4 l = *(const float4*)(logits + (size_t)(g0 + r) * DIM + 4 * t);
        const float4 u = *(const float4*)(noise  + (size_t)(g0 + r) * DIM + 4 * t);
        ushort4_t e;
        e.x = f2bf(__expf(l.x) * __builtin_amdgcn_rcpf(EPSF - __logf(u.x + EPSF)));
        e.y = f2bf(__expf(l.y) * __builtin_amdgcn_rcpf(EPSF - __logf(u.y + EPSF)));
        e.z = f2bf(__expf(l.z) * __builtin_amdgcn_rcpf(EPSF - __logf(u.z + EPSF)));
        e.w = f2bf(__expf(l.w) * __builtin_amdgcn_rcpf(EPSF - __logf(u.w + EPSF)));
        *(ushort4_t*)&lm[r][4 * t] = e;
        ec[r] = e;
    }
    *(float4*)&lw[4 * t] = make_float4(1.f, 1.f, 1.f, 1.f);
    __syncthreads();

    for (int it = 0; it < NITER; ++it) {
        const unsigned tg = (unsigned)(it + 1);

        // ---------- row sums: wave w <-> row w, FMA pass, shfl butterfly ----
        {
            float4 s4 = make_float4(0.f, 0.f, 0.f, 0.f);
#pragma unroll
            for (int k = 0; k < 16; ++k) {
                const int col = (k * 64 + lane) * 4;
                const ushort4_t e  = *(const ushort4_t*)&lm[wave][col];
                const float4    w4 = *(const float4*)&lw[col];
                s4.x += bf2f(e.x) * w4.x;
                s4.y += bf2f(e.y) * w4.y;
                s4.z += bf2f(e.z) * w4.z;
                s4.w += bf2f(e.w) * w4.w;
            }
            float s = (s4.x + s4.y) + (s4.z + s4.w);
#pragma unroll
            for (int o = 1; o < 64; o <<= 1) s += __shfl_xor(s, o, 64);
            if (lane == 0) ru[wave] = __builtin_amdgcn_rcpf(s);
        }
        __syncthreads();

        // ---------- col partials from registers -> tagged publish ----------
        // 4 u64 stores/thread = 32 B dense; wave = 2 KiB contiguous
        {
            float4 p = make_float4(0.f, 0.f, 0.f, 0.f);
#pragma unroll
            for (int r2 = 0; r2 < RPB; ++r2) {
                const ushort4_t e = ec[r2];
                const float uu = ru[r2];
                p.x += bf2f(e.x) * uu;
                p.y += bf2f(e.y) * uu;
                p.z += bf2f(e.z) * uu;
                p.w += bf2f(e.w) * uu;
            }
            u64* pp = part + (size_t)b * DIM + 4 * t;
            st_tag(pp + 0, p.x, tg);
            st_tag(pp + 1, p.y, tg);
            st_tag(pp + 2, p.z, tg);
            st_tag(pp + 3, p.w, tg);
        }

        // ---------- combine: poll IS the data read (no barrier, no drain) ----
        // thread t: row r=t>>2, group g=t&3 -> 4 u64 = 32 B dense
        {
            const int r = t >> 2, g = t & 3;
            const u64* q = part + (size_t)r * DIM + 16 * b + 4 * g;
            u64 v0, v1, v2, v3;
            for (;;) {
                v0 = ld64(q + 0); v1 = ld64(q + 1);
                v2 = ld64(q + 2); v3 = ld64(q + 3);
                if (tag_of(v0) >= tg && tag_of(v1) >= tg &&
                    tag_of(v2) >= tg && tag_of(v3) >= tg) break;
                __builtin_amdgcn_s_sleep(1);
            }
            float4 s4 = make_float4(val_of(v0), val_of(v1), val_of(v2), val_of(v3));
#pragma unroll
            for (int o = 4; o < 64; o <<= 1) {   // sum the wave's 16 rows
                s4.x += __shfl_xor(s4.x, o, 64);
                s4.y += __shfl_xor(s4.y, o, 64);
                s4.z += __shfl_xor(s4.z, o, 64);
                s4.w += __shfl_xor(s4.w, o, 64);
            }
            if (lane < 4) red[wave][lane] = s4;
        }
        __syncthreads();
        if (t < 64) {                            // wave 0: reduce across 16 waves
            float4 s4 = red[t >> 2][t & 3];
#pragma unroll
            for (int o = 4; o < 64; o <<= 1) {
                s4.x += __shfl_xor(s4.x, o, 64);
                s4.y += __shfl_xor(s4.y, o, 64);
                s4.z += __shfl_xor(s4.z, o, 64);
                s4.w += __shfl_xor(s4.w, o, 64);
            }
            if (t < 4) {                         // publish w = 1/colsum, tagged
                float w0 = __builtin_amdgcn_rcpf(s4.x);
                float w1 = __builtin_amdgcn_rcpf(s4.y);
                float w2 = __builtin_amdgcn_rcpf(s4.z);
                float w3 = __builtin_amdgcn_rcpf(s4.w);
                u64* cq = cgt + 16 * b + 4 * t;
                st_tag(cq + 0, w0, tg);
                st_tag(cq + 1, w1, tg);
                st_tag(cq + 2, w2, tg);
                st_tag(cq + 3, w3, tg);
                // self-block shortcut: own columns land in LDS directly
                const int j0 = 16 * b + 4 * t;
                lw[j0 + 0] = w0; lw[j0 + 1] = w1; lw[j0 + 2] = w2; lw[j0 + 3] = w3;
            }
        }

        // ---------- refresh: thread t polls only ITS 4 tagged words ----------
        if ((t >> 2) != b) {       // own columns already in lw via shortcut
            const u64* cq = cgt + 4 * t;
            u64 v0, v1, v2, v3;
            for (;;) {
                v0 = ld64(cq + 0); v1 = ld64(cq + 1);
                v2 = ld64(cq + 2); v3 = ld64(cq + 3);
                if (tag_of(v0) >= tg && tag_of(v1) >= tg &&
                    tag_of(v2) >= tg && tag_of(v3) >= tg) break;
                __builtin_amdgcn_s_sleep(1);
            }
            lw[4 * t + 0] = val_of(v0);
            lw[4 * t + 1] = val_of(v1);
            lw[4 * t + 2] = val_of(v2);
            lw[4 * t + 3] = val_of(v3);
        }
        __syncthreads();
    }

    // ---------- final: out = E * u_i * w_j (E from registers) ----------
    const float4 w4 = *(const float4*)&lw[4 * t];
#pragma unroll
    for (int r = 0; r < RPB; ++r) {
        const ushort4_t e = ec[r];
        const float uu = ru[r];
        float4 o;
        o.x = bf2f(e.x) * (uu * w4.x);
        o.y = bf2f(e.y) * (uu * w4.y);
        o.z = bf2f(e.z) * (uu * w4.z);
        o.w = bf2f(e.w) * (uu * w4.w);
        *(float4*)(out + (size_t)(g0 + r) * DIM + 4 * t) = o;
    }
}

// =================== fallback pipeline (round-1, known-good 769 us) ==============
__device__ __forceinline__ float waveMaxF(float v) {
#pragma unroll
    for (int o = 32; o > 0; o >>= 1) v = fmaxf(v, __shfl_down(v, o, 64));
    return v;
}
__device__ __forceinline__ float waveSumF(float v) {
#pragma unroll
    for (int o = 32; o > 0; o >>= 1) v += __shfl_down(v, o, 64);
    return v;
}

__global__ __launch_bounds__(256) void init_k(const float* __restrict__ logits,
                                              const float* __restrict__ noise,
                                              float* __restrict__ L0,
                                              float* __restrict__ c) {
    int idx = blockIdx.x * blockDim.x + threadIdx.x;
    int stride = gridDim.x * blockDim.x;
    const float4* l4 = (const float4*)logits;
    const float4* n4 = (const float4*)noise;
    float4* o4 = (float4*)L0;
    for (int p = idx; p < DIM * DIM / 4; p += stride) {
        float4 l = l4[p];
        float4 u = n4[p];
        float4 o;
        o.x = l.x - __logf(-__logf(u.x + EPSF) + EPSF);
        o.y = l.y - __logf(-__logf(u.y + EPSF) + EPSF);
        o.z = l.z - __logf(-__logf(u.z + EPSF) + EPSF);
        o.w = l.w - __logf(-__logf(u.w + EPSF) + EPSF);
        o4[p] = o;
    }
    if (idx < DIM) c[idx] = 0.0f;
}

__global__ __launch_bounds__(256) void row_lse(const float* __restrict__ L0,
                                               const float* __restrict__ c,
                                               float* __restrict__ r) {
    __shared__ float red[8];
    const int row = blockIdx.x;
    const int t = threadIdx.x;
    const float4* a4 = (const float4*)(L0 + (size_t)row * DIM);
    const float4* c4 = (const float4*)c;
    float v[16];
    float m = -INFINITY;
#pragma unroll
    for (int k = 0; k < 4; ++k) {
        float4 a  = a4[t + k * 256];
        float4 cc = c4[t + k * 256];
        v[4 * k + 0] = a.x - cc.x;
        v[4 * k + 1] = a.y - cc.y;
        v[4 * k + 2] = a.z - cc.z;
        v[4 * k + 3] = a.w - cc.w;
        m = fmaxf(m, fmaxf(fmaxf(v[4 * k], v[4 * k + 1]), fmaxf(v[4 * k + 2], v[4 * k + 3])));
    }
    m = waveMaxF(m);
    const int lane = t & 63, wid = t >> 6;
    if (lane == 0) red[wid] = m;
    __syncthreads();
    const float bm = fmaxf(fmaxf(red[0], red[1]), fmaxf(red[2], red[3]));
    float s = 0.0f;
#pragma unroll
    for (int q = 0; q < 16; ++q) s += __expf(v[q] - bm);
    s = waveSumF(s);
    if (lane == 0) red[4 + wid] = s;
    __syncthreads();
    if (t == 0) r[row] = bm + __logf(red[4] + red[5] + red[6] + red[7]);
}

__global__ __launch_bounds__(1024) void col_partial(const float* __restrict__ L0,
                                                    const float* __restrict__ r,
                                                    float2* __restrict__ part) {
    __shared__ float sr[256];
    __shared__ float smm[1024];
    __shared__ float sms[1024];
    const int g = blockIdx.x, h = blockIdx.y;
    const int tc = threadIdx.x & 255;
    const int ln = threadIdx.x >> 8;
    if (threadIdx.x < 256) sr[threadIdx.x] = r[h * 256 + threadIdx.x];
    __syncthreads();
    const int j = g * 256 + tc;
    float m = -INFINITY, s = 0.0f;
#pragma unroll 4
    for (int k = 0; k < 64; ++k) {
        int ii = k * 4 + ln;
        float v = L0[(size_t)(h * 256 + ii) * DIM + j] - sr[ii];
        float nm = fmaxf(m, v);
        s = s * __expf(m - nm) + __expf(v - nm);
        m = nm;
    }
    smm[threadIdx.x] = m;
    sms[threadIdx.x] = s;
    __syncthreads();
    if (threadIdx.x < 256) {
        float m0 = smm[tc], m1 = smm[tc + 256], m2 = smm[tc + 512], m3 = smm[tc + 768];
        float M = fmaxf(fmaxf(m0, m1), fmaxf(m2, m3));
        float S = sms[tc] * __expf(m0 - M) + sms[tc + 256] * __expf(m1 - M) +
                  sms[tc + 512] * __expf(m2 - M) + sms[tc + 768] * __expf(m3 - M);
        part[h * DIM + j] = make_float2(M, S);
    }
}

__global__ __launch_bounds__(256) void col_combine(const float2* __restrict__ part,
                                                   float* __restrict__ c) {
    int j = blockIdx.x * 256 + threadIdx.x;
    float pm[NRG], ps[NRG];
    float M = -INFINITY;
#pragma unroll
    for (int h = 0; h < NRG; ++h) {
        float2 p = part[h * DIM + j];
        pm[h] = p.x; ps[h] = p.y;
        M = fmaxf(M, p.x);
    }
    float S = 0.0f;
#pragma unroll
    for (int h = 0; h < NRG; ++h) S += ps[h] * __expf(pm[h] - M);
    c[j] = M + __logf(S);
}

__global__ __launch_bounds__(256) void final_exp(float* __restrict__ L0,
                                                 const float* __restrict__ r,
                                                 const float* __restrict__ c) {
    const float4* c4 = (const float4*)c;
    float4* a4 = (float4*)L0;
    int idx = blockIdx.x * blockDim.x + threadIdx.x;
    int stride = gridDim.x * blockDim.x;
    for (int p = idx; p < DIM * DIM / 4; p += stride) {
        int i  = p >> 10;
        int j4 = p & 1023;
        float4 a = a4[p];
        float rrv = r[i];
        float4 ccv = c4[j4];
        a.x = __expf(a.x - rrv - ccv.x);
        a.y = __expf(a.y - rrv - ccv.y);
        a.z = __expf(a.z - rrv - ccv.z);
        a.w = __expf(a.w - rrv - ccv.w);
        a4[p] = a;
    }
}

// ====================================== launch ===================================
extern "C" void kernel_launch(void* const* d_in, const int* in_sizes, int n_in,
                              void* d_out, int out_size, void* d_ws, size_t ws_size,
                              hipStream_t stream) {
    const float* logits = (const float*)d_in[0];
    const float* noise  = (const float*)d_in[1];
    float* out = (float*)d_out;

    bool tried_flow = false;
    if (ws_size >= 32768) {
        u64* cgt  = (u64*)d_ws;           // 32 KiB tagged w vector
        u64* part = (u64*)d_out;          // first 8 MiB of out = tagged partials
        zero_scratch<<<2048, 256, 0, stream>>>(part, cgt);
        void* args[] = { (void*)&logits, (void*)&noise, (void*)&out,
                         (void*)&cgt, (void*)&part };
        hipError_t err = hipLaunchCooperativeKernel((const void*)sinkhorn_flow,
                                                    dim3(NB), dim3(NT), args, 0, stream);
        tried_flow = (err == hipSuccess);
    }
    if (!tried_flow) {
        // fallback: round-1 multi-kernel pipeline (known-good)
        float* ws = (float*)d_ws;
        float*  r    = ws;
        float*  cf   = ws + DIM;
        float2* part = (float2*)(ws + 2 * DIM);
        init_k<<<4096, 256, 0, stream>>>(logits, noise, out, cf);
        for (int t = 0; t < NITER; ++t) {
            row_lse<<<DIM, 256, 0, stream>>>(out, cf, r);
            col_partial<<<dim3(16, 16), 1024, 0, stream>>>(out, r, part);
            col_combine<<<16, 256, 0, stream>>>(part, cf);
        }
        final_exp<<<4096, 256, 0, stream>>>(out, r, cf);
    }
}

// Round 5
// 509.721 us; speedup vs baseline: 1.4438x; 1.4438x over previous
//
#include <hip/hip_runtime.h>
#include <math.h>

#define DIM   4096
#define NITER 20
#define EPSF  1e-10f
#define NB    256
#define NT    1024
#define RPB   16           // rows per block
#define NRG   16           // fallback path

typedef __attribute__((ext_vector_type(4))) unsigned short ushort4_t;
typedef unsigned long long u64;

// ---------- bf16 <-> f32 (range to 2^127 covers E=exp(la) spread) ----------
__device__ __forceinline__ float bf2f(unsigned short b) {
    unsigned int x = ((unsigned int)b) << 16;
    return __builtin_bit_cast(float, x);
}
__device__ __forceinline__ unsigned short f2bf(float f) {
    unsigned int x = __builtin_bit_cast(unsigned int, f);
    x += 0x7fffu + ((x >> 16) & 1u);          // round-to-nearest-even
    return (unsigned short)(x >> 16);
}

// ---------- MALL-coherent access (agent scope bypasses non-coherent L2) ----------
__device__ __forceinline__ u64 ld64(const u64* p) {
    return __hip_atomic_load(p, __ATOMIC_RELAXED, __HIP_MEMORY_SCOPE_AGENT);
}
// tagged dataflow atom: (tag<<32 | f32). Payload + readiness in ONE load.
// LEDGER: publishes must be per-instruction lane-dense (adjacent lanes ->
// adjacent addresses); interleaved 8-B atomics inflate WRITE_SIZE ~4x (r2,r4).
__device__ __forceinline__ void st_tag(u64* p, float v, unsigned tag) {
    u64 w = ((u64)tag << 32) | (u64)__builtin_bit_cast(unsigned int, v);
    __hip_atomic_store(p, w, __ATOMIC_RELAXED, __HIP_MEMORY_SCOPE_AGENT);
}
__device__ __forceinline__ unsigned tag_of(u64 v) { return (unsigned)(v >> 32); }
__device__ __forceinline__ float    val_of(u64 v) {
    return __builtin_bit_cast(float, (unsigned int)(v & 0xffffffffull));
}

// zero tagged vectors: ug (4096 u64, tail of out) + cgt (4096 u64, in ws)
__global__ __launch_bounds__(256) void zero_scratch(u64* ug, u64* cgt) {
    int idx = blockIdx.x * 256 + threadIdx.x;
    if (idx < DIM) { ug[idx] = 0ull; cgt[idx] = 0ull; }
}

// ============ persistent multiplicative Sinkhorn, dual-slice ownership ==========
// Block b owns rows 16b..16b+15 (bf16 in LDS, feeds row sums + final) AND
// cols 16b..16b+15 (bf16 in REGISTERS et[], feeds col sums). Per iteration:
//   rowstep:  u_i = 1/sum_j E_ij w_j   (local)  -> publish u[16] tagged (128 B)
//   all blocks poll all 4096 tagged u -> lw (lu)
//   colstep:  colsum_j = sum_i E_ij u_i (LOCAL: registers, no partial exchange)
//             w_j = 1/colsum           -> publish w[16] tagged (128 B)
//   refresh:  poll all 4096 tagged w -> lw
// No barriers, no bulk partial exchange. ABA safety: u slot rewrite (tag it+2)
// requires rowstep(it+2) <- all w(it+1) <- every block's colstep(it+1) consumed
// all u(it+1); symmetric for w. ug lives in out's tail: final stores are gated
// behind refresh(NITER) <- all w(NITER) <- all colstep(NITER) done with ug.
__global__ __launch_bounds__(NT, 4) void sinkhorn_flow(
        const float* __restrict__ logits, const float* __restrict__ noise,
        float* __restrict__ out, u64* __restrict__ cgt, u64* __restrict__ ug) {
    __shared__ unsigned short lm[RPB][DIM];  // 128 KiB: block's 16 rows of E (bf16)
    __shared__ float          lw[DIM];       //  16 KiB: w during rowstep, u during colstep
    __shared__ float          ru[RPB];       // row reciprocals u_i (own 16 rows)
    __shared__ float4         red[16][4];    //   1 KiB: colstep cross-wave stage

    const int t = threadIdx.x;
    const int b = blockIdx.x;
    const int wave = t >> 6, lane = t & 63;
    const int g0 = b * RPB;
    const int c  = t & 3;        // col group within own 16 cols
    const int rg = t >> 2;       // row group 0..255 (16 rows each)

    // ---- init A: own ROWS -> lm (coalesced, one full-matrix read) ----
#pragma unroll
    for (int r = 0; r < RPB; ++r) {
        const float4 l = *(const float4*)(logits + (size_t)(g0 + r) * DIM + 4 * t);
        const float4 u = *(const float4*)(noise  + (size_t)(g0 + r) * DIM + 4 * t);
        ushort4_t e;
        e.x = f2bf(__expf(l.x) * __builtin_amdgcn_rcpf(EPSF - __logf(u.x + EPSF)));
        e.y = f2bf(__expf(l.y) * __builtin_amdgcn_rcpf(EPSF - __logf(u.y + EPSF)));
        e.z = f2bf(__expf(l.z) * __builtin_amdgcn_rcpf(EPSF - __logf(u.z + EPSF)));
        e.w = f2bf(__expf(l.w) * __builtin_amdgcn_rcpf(EPSF - __logf(u.w + EPSF)));
        *(ushort4_t*)&lm[r][4 * t] = e;
    }

    // ---- init B: own COLS -> registers (64-B segments, no duplication) ----
    // thread t: cols 16b+4c..+3, rows rg*16..rg*16+15. Same f2bf formula =>
    // bit-identical E values as the row slice (deterministic).
    ushort4_t et[RPB];
    {
        const int j0 = 16 * b + 4 * c;
#pragma unroll
        for (int k = 0; k < RPB; ++k) {
            const size_t row = (size_t)(rg * 16 + k);
            const float4 l = *(const float4*)(logits + row * DIM + j0);
            const float4 u = *(const float4*)(noise  + row * DIM + j0);
            ushort4_t e;
            e.x = f2bf(__expf(l.x) * __builtin_amdgcn_rcpf(EPSF - __logf(u.x + EPSF)));
            e.y = f2bf(__expf(l.y) * __builtin_amdgcn_rcpf(EPSF - __logf(u.y + EPSF)));
            e.z = f2bf(__expf(l.z) * __builtin_amdgcn_rcpf(EPSF - __logf(u.z + EPSF)));
            e.w = f2bf(__expf(l.w) * __builtin_amdgcn_rcpf(EPSF - __logf(u.w + EPSF)));
            et[k] = e;
        }
    }
    *(float4*)&lw[4 * t] = make_float4(1.f, 1.f, 1.f, 1.f);
    __syncthreads();

    for (int it = 0; it < NITER; ++it) {
        const unsigned tg = (unsigned)(it + 1);

        // ---------- rowstep: wave w <-> row w, FMA pass, shfl butterfly ----
        {
            float4 s4 = make_float4(0.f, 0.f, 0.f, 0.f);
#pragma unroll
            for (int k = 0; k < 16; ++k) {
                const int col = (k * 64 + lane) * 4;
                const ushort4_t e  = *(const ushort4_t*)&lm[wave][col];
                const float4    w4 = *(const float4*)&lw[col];
                s4.x += bf2f(e.x) * w4.x;
                s4.y += bf2f(e.y) * w4.y;
                s4.z += bf2f(e.z) * w4.z;
                s4.w += bf2f(e.w) * w4.w;
            }
            float s = (s4.x + s4.y) + (s4.z + s4.w);
#pragma unroll
            for (int o = 1; o < 64; o <<= 1) s += __shfl_xor(s, o, 64);
            if (lane == 0) ru[wave] = __builtin_amdgcn_rcpf(s);
        }
        __syncthreads();   // ru complete; lw(w) now dead -> may be reused for u

        // ---------- publish u: 16 lanes, 128 B lane-dense tagged ----------
        if (t < 16) st_tag(ug + 16 * b + t, ru[t], tg);

        // ---------- u-poll: thread t<256 owns chunk t (16 words) -> lw ----
        if (t < 256) {
            float* dst = lw + 16 * t;
            if (t == b) {      // own u: no MALL round-trip
#pragma unroll
                for (int k = 0; k < 16; ++k) dst[k] = ru[k];
            } else {
                const u64* q = ug + 16 * t;
#pragma unroll
                for (int h = 0; h < 2; ++h) {   // two halves of 8: caps VGPR
                    u64 v0, v1, v2, v3, v4, v5, v6, v7;
                    for (;;) {
                        v0 = ld64(q + 8*h + 0); v1 = ld64(q + 8*h + 1);
                        v2 = ld64(q + 8*h + 2); v3 = ld64(q + 8*h + 3);
                        v4 = ld64(q + 8*h + 4); v5 = ld64(q + 8*h + 5);
                        v6 = ld64(q + 8*h + 6); v7 = ld64(q + 8*h + 7);
                        if (tag_of(v0) >= tg && tag_of(v1) >= tg &&
                            tag_of(v2) >= tg && tag_of(v3) >= tg &&
                            tag_of(v4) >= tg && tag_of(v5) >= tg &&
                            tag_of(v6) >= tg && tag_of(v7) >= tg) break;
                        __builtin_amdgcn_s_sleep(1);
                    }
                    dst[8*h + 0] = val_of(v0); dst[8*h + 1] = val_of(v1);
                    dst[8*h + 2] = val_of(v2); dst[8*h + 3] = val_of(v3);
                    dst[8*h + 4] = val_of(v4); dst[8*h + 5] = val_of(v5);
                    dst[8*h + 6] = val_of(v6); dst[8*h + 7] = val_of(v7);
                }
            }
        }
        __syncthreads();   // lw now holds u[0..4095]

        // ---------- colstep: LOCAL col sums from registers ----------
        {
            float4 p = make_float4(0.f, 0.f, 0.f, 0.f);
            const int r0 = rg * 16;
#pragma unroll
            for (int k = 0; k < 16; ++k) {
                const float uu = lw[r0 + k];
                const ushort4_t e = et[k];
                p.x += bf2f(e.x) * uu;
                p.y += bf2f(e.y) * uu;
                p.z += bf2f(e.z) * uu;
                p.w += bf2f(e.w) * uu;
            }
#pragma unroll
            for (int o = 4; o < 64; o <<= 1) {   // reduce 16 row-groups in wave
                p.x += __shfl_xor(p.x, o, 64);
                p.y += __shfl_xor(p.y, o, 64);
                p.z += __shfl_xor(p.z, o, 64);
                p.w += __shfl_xor(p.w, o, 64);
            }
            if (lane < 4) red[wave][lane] = p;
        }
        __syncthreads();   // colstep's lw reads done; lw may be refreshed with w
        if (t < 64) {                            // wave 0: reduce across 16 waves
            float4 s4 = red[t >> 2][t & 3];
#pragma unroll
            for (int o = 4; o < 64; o <<= 1) {
                s4.x += __shfl_xor(s4.x, o, 64);
                s4.y += __shfl_xor(s4.y, o, 64);
                s4.z += __shfl_xor(s4.z, o, 64);
                s4.w += __shfl_xor(s4.w, o, 64);
            }
            if (t < 4) {                         // publish w = 1/colsum, tagged
                float w0 = __builtin_amdgcn_rcpf(s4.x);
                float w1 = __builtin_amdgcn_rcpf(s4.y);
                float w2 = __builtin_amdgcn_rcpf(s4.z);
                float w3 = __builtin_amdgcn_rcpf(s4.w);
                u64* cq = cgt + 16 * b + 4 * t;
                st_tag(cq + 0, w0, tg);
                st_tag(cq + 1, w1, tg);
                st_tag(cq + 2, w2, tg);
                st_tag(cq + 3, w3, tg);
                // self-block shortcut: own columns land in LDS directly
                const int j0 = 16 * b + 4 * t;
                lw[j0 + 0] = w0; lw[j0 + 1] = w1; lw[j0 + 2] = w2; lw[j0 + 3] = w3;
            }
        }

        // ---------- refresh: thread t polls only ITS 4 tagged w words ----------
        if ((t >> 2) != b) {       // own columns already in lw via shortcut
            const u64* cq = cgt + 4 * t;
            u64 v0, v1, v2, v3;
            for (;;) {
                v0 = ld64(cq + 0); v1 = ld64(cq + 1);
                v2 = ld64(cq + 2); v3 = ld64(cq + 3);
                if (tag_of(v0) >= tg && tag_of(v1) >= tg &&
                    tag_of(v2) >= tg && tag_of(v3) >= tg) break;
                __builtin_amdgcn_s_sleep(1);
            }
            lw[4 * t + 0] = val_of(v0);
            lw[4 * t + 1] = val_of(v1);
            lw[4 * t + 2] = val_of(v2);
            lw[4 * t + 3] = val_of(v3);
        }
        __syncthreads();   // lw holds w(it+1)
    }

    // ---------- final: out = E * u_i * w_j (row slice from LDS) ----------
    const float4 w4 = *(const float4*)&lw[4 * t];
#pragma unroll
    for (int r = 0; r < RPB; ++r) {
        const ushort4_t e = *(const ushort4_t*)&lm[r][4 * t];
        const float uu = ru[r];
        float4 o;
        o.x = bf2f(e.x) * (uu * w4.x);
        o.y = bf2f(e.y) * (uu * w4.y);
        o.z = bf2f(e.z) * (uu * w4.z);
        o.w = bf2f(e.w) * (uu * w4.w);
        *(float4*)(out + (size_t)(g0 + r) * DIM + 4 * t) = o;
    }
}

// =================== fallback pipeline (round-1, known-good 769 us) ==============
__device__ __forceinline__ float waveMaxF(float v) {
#pragma unroll
    for (int o = 32; o > 0; o >>= 1) v = fmaxf(v, __shfl_down(v, o, 64));
    return v;
}
__device__ __forceinline__ float waveSumF(float v) {
#pragma unroll
    for (int o = 32; o > 0; o >>= 1) v += __shfl_down(v, o, 64);
    return v;
}

__global__ __launch_bounds__(256) void init_k(const float* __restrict__ logits,
                                              const float* __restrict__ noise,
                                              float* __restrict__ L0,
                                              float* __restrict__ c) {
    int idx = blockIdx.x * blockDim.x + threadIdx.x;
    int stride = gridDim.x * blockDim.x;
    const float4* l4 = (const float4*)logits;
    const float4* n4 = (const float4*)noise;
    float4* o4 = (float4*)L0;
    for (int p = idx; p < DIM * DIM / 4; p += stride) {
        float4 l = l4[p];
        float4 u = n4[p];
        float4 o;
        o.x = l.x - __logf(-__logf(u.x + EPSF) + EPSF);
        o.y = l.y - __logf(-__logf(u.y + EPSF) + EPSF);
        o.z = l.z - __logf(-__logf(u.z + EPSF) + EPSF);
        o.w = l.w - __logf(-__logf(u.w + EPSF) + EPSF);
        o4[p] = o;
    }
    if (idx < DIM) c[idx] = 0.0f;
}

__global__ __launch_bounds__(256) void row_lse(const float* __restrict__ L0,
                                               const float* __restrict__ c,
                                               float* __restrict__ r) {
    __shared__ float red[8];
    const int row = blockIdx.x;
    const int t = threadIdx.x;
    const float4* a4 = (const float4*)(L0 + (size_t)row * DIM);
    const float4* c4 = (const float4*)c;
    float v[16];
    float m = -INFINITY;
#pragma unroll
    for (int k = 0; k < 4; ++k) {
        float4 a  = a4[t + k * 256];
        float4 cc = c4[t + k * 256];
        v[4 * k + 0] = a.x - cc.x;
        v[4 * k + 1] = a.y - cc.y;
        v[4 * k + 2] = a.z - cc.z;
        v[4 * k + 3] = a.w - cc.w;
        m = fmaxf(m, fmaxf(fmaxf(v[4 * k], v[4 * k + 1]), fmaxf(v[4 * k + 2], v[4 * k + 3])));
    }
    m = waveMaxF(m);
    const int lane = t & 63, wid = t >> 6;
    if (lane == 0) red[wid] = m;
    __syncthreads();
    const float bm = fmaxf(fmaxf(red[0], red[1]), fmaxf(red[2], red[3]));
    float s = 0.0f;
#pragma unroll
    for (int q = 0; q < 16; ++q) s += __expf(v[q] - bm);
    s = waveSumF(s);
    if (lane == 0) red[4 + wid] = s;
    __syncthreads();
    if (t == 0) r[row] = bm + __logf(red[4] + red[5] + red[6] + red[7]);
}

__global__ __launch_bounds__(1024) void col_partial(const float* __restrict__ L0,
                                                    const float* __restrict__ r,
                                                    float2* __restrict__ part) {
    __shared__ float sr[256];
    __shared__ float smm[1024];
    __shared__ float sms[1024];
    const int g = blockIdx.x, h = blockIdx.y;
    const int tc = threadIdx.x & 255;
    const int ln = threadIdx.x >> 8;
    if (threadIdx.x < 256) sr[threadIdx.x] = r[h * 256 + threadIdx.x];
    __syncthreads();
    const int j = g * 256 + tc;
    float m = -INFINITY, s = 0.0f;
#pragma unroll 4
    for (int k = 0; k < 64; ++k) {
        int ii = k * 4 + ln;
        float v = L0[(size_t)(h * 256 + ii) * DIM + j] - sr[ii];
        float nm = fmaxf(m, v);
        s = s * __expf(m - nm) + __expf(v - nm);
        m = nm;
    }
    smm[threadIdx.x] = m;
    sms[threadIdx.x] = s;
    __syncthreads();
    if (threadIdx.x < 256) {
        float m0 = smm[tc], m1 = smm[tc + 256], m2 = smm[tc + 512], m3 = smm[tc + 768];
        float M = fmaxf(fmaxf(m0, m1), fmaxf(m2, m3));
        float S = sms[tc] * __expf(m0 - M) + sms[tc + 256] * __expf(m1 - M) +
                  sms[tc + 512] * __expf(m2 - M) + sms[tc + 768] * __expf(m3 - M);
        part[h * DIM + j] = make_float2(M, S);
    }
}

__global__ __launch_bounds__(256) void col_combine(const float2* __restrict__ part,
                                                   float* __restrict__ c) {
    int j = blockIdx.x * 256 + threadIdx.x;
    float pm[NRG], ps[NRG];
    float M = -INFINITY;
#pragma unroll
    for (int h = 0; h < NRG; ++h) {
        float2 p = part[h * DIM + j];
        pm[h] = p.x; ps[h] = p.y;
        M = fmaxf(M, p.x);
    }
    float S = 0.0f;
#pragma unroll
    for (int h = 0; h < NRG; ++h) S += ps[h] * __expf(pm[h] - M);
    c[j] = M + __logf(S);
}

__global__ __launch_bounds__(256) void final_exp(float* __restrict__ L0,
                                                 const float* __restrict__ r,
                                                 const float* __restrict__ c) {
    const float4* c4 = (const float4*)c;
    float4* a4 = (float4*)L0;
    int idx = blockIdx.x * blockDim.x + threadIdx.x;
    int stride = gridDim.x * blockDim.x;
    for (int p = idx; p < DIM * DIM / 4; p += stride) {
        int i  = p >> 10;
        int j4 = p & 1023;
        float4 a = a4[p];
        float rrv = r[i];
        float4 ccv = c4[j4];
        a.x = __expf(a.x - rrv - ccv.x);
        a.y = __expf(a.y - rrv - ccv.y);
        a.z = __expf(a.z - rrv - ccv.z);
        a.w = __expf(a.w - rrv - ccv.w);
        a4[p] = a;
    }
}

// ====================================== launch ===================================
extern "C" void kernel_launch(void* const* d_in, const int* in_sizes, int n_in,
                              void* d_out, int out_size, void* d_ws, size_t ws_size,
                              hipStream_t stream) {
    const float* logits = (const float*)d_in[0];
    const float* noise  = (const float*)d_in[1];
    float* out = (float*)d_out;

    bool tried_flow = false;
    if (ws_size >= 32768) {
        u64* cgt = (u64*)d_ws;                                    // 32 KiB tagged w
        u64* ug  = (u64*)d_out + ((size_t)DIM * DIM / 2 - DIM);   // 32 KiB tagged u (out tail)
        zero_scratch<<<16, 256, 0, stream>>>(ug, cgt);
        void* args[] = { (void*)&logits, (void*)&noise, (void*)&out,
                         (void*)&cgt, (void*)&ug };
        hipError_t err = hipLaunchCooperativeKernel((const void*)sinkhorn_flow,
                                                    dim3(NB), dim3(NT), args, 0, stream);
        tried_flow = (err == hipSuccess);
    }
    if (!tried_flow) {
        // fallback: round-1 multi-kernel pipeline (known-good)
        float* ws = (float*)d_ws;
        float*  r    = ws;
        float*  cf   = ws + DIM;
        float2* part = (float2*)(ws + 2 * DIM);
        init_k<<<4096, 256, 0, stream>>>(logits, noise, out, cf);
        for (int t = 0; t < NITER; ++t) {
            row_lse<<<DIM, 256, 0, stream>>>(out, cf, r);
            col_partial<<<dim3(16, 16), 1024, 0, stream>>>(out, r, part);
            col_combine<<<16, 256, 0, stream>>>(part, cf);
        }
        final_exp<<<4096, 256, 0, stream>>>(out, r, cf);
    }
}